// Round 1
// baseline (377.376 us; speedup 1.0000x reference)
//
#include <hip/hip_runtime.h>

// NormalizationLayer: out = (v, exp(-adj^2 * c)), c = 1/(2*(100*sigmoid(s)+1e-5)^2),
// s = (v W1^T)(v W2^T)^T = v (W1^T W2) v^T = (v M) v^T.
//
// Strategy: fold W1,W2 into M once; u = v*M (small GEMM); fused big GEMM
// s = u*v^T with sigmoid/exp/adj epilogue (s never hits HBM). f16 MFMA
// (fp32 acc) — bf16 would be precision-borderline, fp32 VALU is 3x too slow.

typedef _Float16 half8_t __attribute__((ext_vector_type(8)));
typedef _Float16 half4_t __attribute__((ext_vector_type(4)));
typedef float floatx4 __attribute__((ext_vector_type(4)));

#define LDSS 72   // LDS row stride in f16 elems (64 + 8 pad -> 16B-aligned, banks balanced)

// ---------------- kernel 1: copy v -> out0, convert v -> f16 ----------------
__global__ void prep_kernel(const float4* __restrict__ v4,
                            float4* __restrict__ out4,
                            half4_t* __restrict__ vf4) {
    int idx = blockIdx.x * 256 + threadIdx.x;   // grid sized exactly: 4096*256 = 4194304/4
    float4 t = v4[idx];
    out4[idx] = t;
    half4_t h;
    h[0] = (_Float16)t.x; h[1] = (_Float16)t.y;
    h[2] = (_Float16)t.z; h[3] = (_Float16)t.w;
    vf4[idx] = h;
}

// ---------------- kernel 2: Mt[j][i] = sum_o W2[o][j] * W1[o][i] ----------------
// (Mt is M^T so the GEMM B-operand reads contiguous K)
__global__ void mt_kernel(const float* __restrict__ W1,
                          const float* __restrict__ W2,
                          _Float16* __restrict__ Mt) {
    __shared__ float w2col[256];
    const int j = blockIdx.x;
    const int i = threadIdx.x;
    w2col[i] = W2[i * 256 + j];
    __syncthreads();
    float acc = 0.f;
    #pragma unroll 8
    for (int o = 0; o < 256; ++o)
        acc += w2col[o] * W1[o * 256 + i];
    Mt[j * 256 + i] = (_Float16)acc;
}

// ---------------- GEMM: C[x][y] = sum_k A[x][k]*B[y][k], K=256, tile 128x128 ----------------
// MODE 0: store C as f16 into Uout (u = v*M). MODE 1: fused epilogue -> out_adj.
template<int MODE>
__global__ __launch_bounds__(256, 2)
void gemm_kernel(const _Float16* __restrict__ A, const _Float16* __restrict__ Bm,
                 size_t a_bstride, size_t b_bstride,
                 _Float16* __restrict__ Uout,
                 const float* __restrict__ adj, float* __restrict__ out) {
    __shared__ _Float16 As[128 * LDSS];
    __shared__ _Float16 Bs[128 * LDSS];

    const int tid  = threadIdx.x;
    const int lane = tid & 63;
    const int wid  = tid >> 6;
    const int wm   = wid >> 1;          // 2x2 wave grid, each wave 64x64
    const int wn   = wid & 1;
    const int quad = lane >> 4;
    const int l16  = lane & 15;

    const int m0 = blockIdx.x * 128;
    const int n0 = blockIdx.y * 128;
    const int batch = blockIdx.z;

    const _Float16* Ab = A  + (size_t)batch * a_bstride;
    const _Float16* Bb = Bm + (size_t)batch * b_bstride;

    floatx4 acc[4][4];
    #pragma unroll
    for (int i = 0; i < 4; ++i)
        #pragma unroll
        for (int j = 0; j < 4; ++j)
            acc[i][j] = (floatx4){0.f, 0.f, 0.f, 0.f};

    const int rrow = tid >> 3;          // staging: 8 threads (8x16B) per 64-col row
    const int ch8  = (tid & 7) * 8;     // f16 offset within row

    for (int kc = 0; kc < 256; kc += 64) {
        __syncthreads();
        #pragma unroll
        for (int r = 0; r < 4; ++r) {
            int row = r * 32 + rrow;
            uint4 va = *(const uint4*)(Ab + (((size_t)(m0 + row)) << 8) + kc + ch8);
            uint4 vb = *(const uint4*)(Bb + (((size_t)(n0 + row)) << 8) + kc + ch8);
            *(uint4*)(&As[row * LDSS + ch8]) = va;
            *(uint4*)(&Bs[row * LDSS + ch8]) = vb;
        }
        __syncthreads();
        #pragma unroll
        for (int ks = 0; ks < 2; ++ks) {
            const int kof = ks * 32 + quad * 8;   // A[m=lane&15][k=quad*8+j] layout
            half8_t af[4], bf[4];
            #pragma unroll
            for (int i = 0; i < 4; ++i) {
                af[i] = *(const half8_t*)(&As[(wm * 64 + i * 16 + l16) * LDSS + kof]);
                bf[i] = *(const half8_t*)(&Bs[(wn * 64 + i * 16 + l16) * LDSS + kof]);
            }
            #pragma unroll
            for (int i = 0; i < 4; ++i)
                #pragma unroll
                for (int j = 0; j < 4; ++j)
                    acc[i][j] = __builtin_amdgcn_mfma_f32_16x16x32_f16(
                        af[i], bf[j], acc[i][j], 0, 0, 0);
        }
    }

    // D layout: row = quad*4 + reg (A side), col = lane&15 (B side)  [m89-verified]
    if (MODE == 0) {
        #pragma unroll
        for (int i = 0; i < 4; ++i) {
            int grow = m0 + wm * 64 + i * 16 + quad * 4;
            #pragma unroll
            for (int j = 0; j < 4; ++j) {
                int gcol = n0 + wn * 64 + j * 16 + l16;
                #pragma unroll
                for (int r = 0; r < 4; ++r)
                    Uout[(size_t)(grow + r) * 256 + gcol] = (_Float16)acc[i][j][r];
            }
        }
    } else {
        const size_t obase = (size_t)batch * 2048 * 2048;
        #pragma unroll
        for (int i = 0; i < 4; ++i) {
            int grow = m0 + wm * 64 + i * 16 + quad * 4;
            #pragma unroll
            for (int j = 0; j < 4; ++j) {
                int gcol = n0 + wn * 64 + j * 16 + l16;
                #pragma unroll
                for (int r = 0; r < 4; ++r) {
                    float s   = acc[i][j][r];
                    float sig = 1.0f / (1.0f + __expf(-s));
                    float p   = 100.0f * sig + 1e-5f;
                    size_t idx = obase + (size_t)(grow + r) * 2048 + gcol;
                    float a = adj[idx];
                    float q = a * __builtin_amdgcn_rcpf(p);
                    out[idx] = __expf(-0.5f * q * q);   // exp(-a^2 / (2 p^2))
                }
            }
        }
    }
}

extern "C" void kernel_launch(void* const* d_in, const int* in_sizes, int n_in,
                              void* d_out, int out_size, void* d_ws, size_t ws_size,
                              hipStream_t stream) {
    const float* v   = (const float*)d_in[0];   // [8,2048,256]
    const float* adj = (const float*)d_in[1];   // [8,2048,2048]
    const float* W1  = (const float*)d_in[2];   // [256,256]
    const float* W2  = (const float*)d_in[3];   // [256,256]

    float* out_v   = (float*)d_out;                              // output 0: v copy
    float* out_adj = (float*)d_out + (size_t)8 * 2048 * 256;     // output 1

    char* ws = (char*)d_ws;
    _Float16* vf = (_Float16*)ws;                          // 8 MiB  [8*2048,256] f16
    _Float16* uf = (_Float16*)(ws + ((size_t)8 << 20));    // 8 MiB  [8*2048,256] f16
    _Float16* Mt = (_Float16*)(ws + ((size_t)16 << 20));   // 128 KiB [256,256] f16 (M^T)

    prep_kernel<<<4096, 256, 0, stream>>>((const float4*)v, (float4*)out_v, (half4_t*)vf);
    mt_kernel<<<256, 256, 0, stream>>>(W1, W2, Mt);
    // u = v * M : A rows = 16384 (all batches flat), B = Mt (256 rows), grid (128,2)
    gemm_kernel<0><<<dim3(128, 2, 1), 256, 0, stream>>>(
        vf, Mt, 0, 0, uf, nullptr, nullptr);
    // s = u * v^T per batch + fused epilogue, grid (16,16,8)
    gemm_kernel<1><<<dim3(16, 16, 8), 256, 0, stream>>>(
        uf, vf, (size_t)2048 * 256, (size_t)2048 * 256, nullptr, adj, out_adj);
}

// Round 2
// 337.556 us; speedup vs baseline: 1.1180x; 1.1180x over previous
//
#include <hip/hip_runtime.h>

// NormalizationLayer: out = (v, exp(-adj^2 * c)), c = 1/(2*(100*sigmoid(s)+1e-5)^2),
// s = (v W1^T)(v W2^T)^T = v (W1^T W2) v^T = (v M) v^T.
//
// R2: swapped MFMA operand roles so each lane's 4 acc regs span 4 consecutive
// output COLUMNS -> float4 adj load / float4 store in the fused epilogue
// (was 64 scalar dwords/lane). launch_bounds(256,4) -> 4 blocks/CU.

typedef _Float16 half8_t __attribute__((ext_vector_type(8)));
typedef _Float16 half4_t __attribute__((ext_vector_type(4)));
typedef float floatx4 __attribute__((ext_vector_type(4)));

#define LDSS 72   // LDS row stride in f16 elems (144 B = 9x16B, b128-aligned)

// ---------------- kernel 1: copy v -> out0, convert v -> f16 ----------------
__global__ void prep_kernel(const float4* __restrict__ v4,
                            float4* __restrict__ out4,
                            half4_t* __restrict__ vf4) {
    int idx = blockIdx.x * 256 + threadIdx.x;   // 4096*256 = 4194304/4 exact
    float4 t = v4[idx];
    out4[idx] = t;
    half4_t h;
    h[0] = (_Float16)t.x; h[1] = (_Float16)t.y;
    h[2] = (_Float16)t.z; h[3] = (_Float16)t.w;
    vf4[idx] = h;
}

// ---------------- kernel 2: Mt[j][i] = sum_o W2[o][j] * W1[o][i] ----------------
__global__ void mt_kernel(const float* __restrict__ W1,
                          const float* __restrict__ W2,
                          _Float16* __restrict__ Mt) {
    __shared__ float w2col[256];
    const int j = blockIdx.x;
    const int i = threadIdx.x;
    w2col[i] = W2[i * 256 + j];
    __syncthreads();
    float acc = 0.f;
    #pragma unroll 8
    for (int o = 0; o < 256; ++o)
        acc += w2col[o] * W1[o * 256 + i];
    Mt[j * 256 + i] = (_Float16)acc;
}

// ---------------- GEMM: C[m][n] = sum_k A[m,k]*Bm[n,k], K=256, tile 128x128 ----
// MFMA operands SWAPPED: A-operand = Bm-frag (n dim), B-operand = A-frag (m dim).
// => D row axis (quad*4+reg) = n (fast output dim), D col axis (l16) = m.
// MODE 0: store half4 into Uout. MODE 1: fused sigmoid/exp epilogue -> out.
template<int MODE>
__global__ __launch_bounds__(256, 4)
void gemm_kernel(const _Float16* __restrict__ A, const _Float16* __restrict__ Bm,
                 size_t a_bstride, size_t b_bstride,
                 _Float16* __restrict__ Uout,
                 const float* __restrict__ adj, float* __restrict__ out) {
    __shared__ _Float16 As[128 * LDSS];   // m-dim tile (A rows)
    __shared__ _Float16 Bs[128 * LDSS];   // n-dim tile (Bm rows)

    const int tid  = threadIdx.x;
    const int lane = tid & 63;
    const int wid  = tid >> 6;
    const int wm   = wid >> 1;          // 2x2 wave grid, each wave 64(m)x64(n)
    const int wn   = wid & 1;
    const int quad = lane >> 4;
    const int l16  = lane & 15;

    const int m0 = blockIdx.x * 128;
    const int n0 = blockIdx.y * 128;
    const int batch = blockIdx.z;

    const _Float16* Ab = A  + (size_t)batch * a_bstride;
    const _Float16* Bb = Bm + (size_t)batch * b_bstride;

    floatx4 acc[4][4];   // acc[i][j]: i -> n-frag, j -> m-frag
    #pragma unroll
    for (int i = 0; i < 4; ++i)
        #pragma unroll
        for (int j = 0; j < 4; ++j)
            acc[i][j] = (floatx4){0.f, 0.f, 0.f, 0.f};

    const int rrow = tid >> 3;          // staging: 8 threads (8x16B) per 64-col row
    const int ch8  = (tid & 7) * 8;

    for (int kc = 0; kc < 256; kc += 64) {
        __syncthreads();
        #pragma unroll
        for (int r = 0; r < 4; ++r) {
            int row = r * 32 + rrow;
            uint4 va = *(const uint4*)(Ab + (((size_t)(m0 + row)) << 8) + kc + ch8);
            uint4 vb = *(const uint4*)(Bb + (((size_t)(n0 + row)) << 8) + kc + ch8);
            *(uint4*)(&As[row * LDSS + ch8]) = va;
            *(uint4*)(&Bs[row * LDSS + ch8]) = vb;
        }
        __syncthreads();
        #pragma unroll
        for (int ks = 0; ks < 2; ++ks) {
            const int kof = ks * 32 + quad * 8;   // operand layout: [row=lane&15][k=quad*8+j]
            half8_t mf[4], nf[4];
            #pragma unroll
            for (int t = 0; t < 4; ++t) {
                mf[t] = *(const half8_t*)(&As[(wm * 64 + t * 16 + l16) * LDSS + kof]);
                nf[t] = *(const half8_t*)(&Bs[(wn * 64 + t * 16 + l16) * LDSS + kof]);
            }
            #pragma unroll
            for (int i = 0; i < 4; ++i)
                #pragma unroll
                for (int j = 0; j < 4; ++j)
                    acc[i][j] = __builtin_amdgcn_mfma_f32_16x16x32_f16(
                        nf[i], mf[j], acc[i][j], 0, 0, 0);   // A-op = n, B-op = m
        }
    }

    // D layout: n = quad*4 + reg (A-operand side), m = l16 (B-operand side)
    if (MODE == 0) {
        #pragma unroll
        for (int j = 0; j < 4; ++j) {
            int m = m0 + wm * 64 + j * 16 + l16;        // u row
            #pragma unroll
            for (int i = 0; i < 4; ++i) {
                int n = wn * 64 + i * 16 + quad * 4;    // u col (grid.y covers n0)
                half4_t h;
                #pragma unroll
                for (int r = 0; r < 4; ++r) h[r] = (_Float16)acc[i][j][r];
                *(half4_t*)(Uout + (size_t)m * 256 + n0 + n) = h;
            }
        }
    } else {
        const size_t obase = (size_t)batch * 2048 * 2048;
        #pragma unroll
        for (int j = 0; j < 4; ++j) {
            int m = m0 + wm * 64 + j * 16 + l16;
            const size_t rbase = obase + (size_t)m * 2048;
            #pragma unroll
            for (int i = 0; i < 4; ++i) {
                int n = n0 + wn * 64 + i * 16 + quad * 4;
                float4 a = *(const float4*)(adj + rbase + n);
                float4 o;
                {
                    float s   = acc[i][j][0];
                    float p   = 100.0f / (1.0f + __expf(-s)) + 1e-5f;
                    float q   = a.x * __builtin_amdgcn_rcpf(p);
                    o.x = __expf(-0.5f * q * q);
                }
                {
                    float s   = acc[i][j][1];
                    float p   = 100.0f / (1.0f + __expf(-s)) + 1e-5f;
                    float q   = a.y * __builtin_amdgcn_rcpf(p);
                    o.y = __expf(-0.5f * q * q);
                }
                {
                    float s   = acc[i][j][2];
                    float p   = 100.0f / (1.0f + __expf(-s)) + 1e-5f;
                    float q   = a.z * __builtin_amdgcn_rcpf(p);
                    o.z = __expf(-0.5f * q * q);
                }
                {
                    float s   = acc[i][j][3];
                    float p   = 100.0f / (1.0f + __expf(-s)) + 1e-5f;
                    float q   = a.w * __builtin_amdgcn_rcpf(p);
                    o.w = __expf(-0.5f * q * q);
                }
                *(float4*)(out + rbase + n) = o;
            }
        }
    }
}

extern "C" void kernel_launch(void* const* d_in, const int* in_sizes, int n_in,
                              void* d_out, int out_size, void* d_ws, size_t ws_size,
                              hipStream_t stream) {
    const float* v   = (const float*)d_in[0];   // [8,2048,256]
    const float* adj = (const float*)d_in[1];   // [8,2048,2048]
    const float* W1  = (const float*)d_in[2];   // [256,256]
    const float* W2  = (const float*)d_in[3];   // [256,256]

    float* out_v   = (float*)d_out;                              // output 0: v copy
    float* out_adj = (float*)d_out + (size_t)8 * 2048 * 256;     // output 1

    char* ws = (char*)d_ws;
    _Float16* vf = (_Float16*)ws;                          // 8 MiB  [8*2048,256] f16
    _Float16* uf = (_Float16*)(ws + ((size_t)8 << 20));    // 8 MiB  [8*2048,256] f16
    _Float16* Mt = (_Float16*)(ws + ((size_t)16 << 20));   // 128 KiB [256,256] f16 (M^T)

    prep_kernel<<<4096, 256, 0, stream>>>((const float4*)v, (float4*)out_v, (half4_t*)vf);
    mt_kernel<<<256, 256, 0, stream>>>(W1, W2, Mt);
    // u = v * M : A rows = 16384 (all batches flat), Bm = Mt (256 rows)
    gemm_kernel<0><<<dim3(128, 2, 1), 256, 0, stream>>>(
        vf, Mt, 0, 0, uf, nullptr, nullptr);
    // s = u * v^T per batch + fused epilogue
    gemm_kernel<1><<<dim3(16, 16, 8), 256, 0, stream>>>(
        uf, vf, (size_t)2048 * 256, (size_t)2048 * 256, nullptr, adj, out_adj);
}

// Round 4
// 311.624 us; speedup vs baseline: 1.2110x; 1.0832x over previous
//
#include <hip/hip_runtime.h>

// NormalizationLayer: out = (v, exp(-adj^2 * c)), c = 1/(2*(100*sigmoid(s)+1e-5)^2),
// s = (v W1^T)(v W2^T)^T = v (W1^T W2) v^T = (v M) v^T.
//
// R4 = R3 with compile fix: __builtin_nontemporal_store needs clang
// ext_vector_type, not HIP_vector_type. Epilogue: p = 100*sigmoid(s)+1e-5
// -> f16 LDS tile (reuses As/Bs space), then fully-coalesced streaming pass
// over adj/out (full 128B lines, pipelineable) with non-temporal stores.

typedef _Float16 half8_t __attribute__((ext_vector_type(8)));
typedef _Float16 half4_t __attribute__((ext_vector_type(4)));
typedef float floatx4 __attribute__((ext_vector_type(4)));

#define LDSS 72   // K-loop LDS row stride in f16 (144 B, b128-aligned, conflict-free)
#define PS   132  // p-tile row stride in f16 (264 B, banks balanced)

// ---------------- kernel 1: copy v -> out0, convert v -> f16 ----------------
__global__ void prep_kernel(const floatx4* __restrict__ v4,
                            floatx4* __restrict__ out4,
                            half4_t* __restrict__ vf4) {
    int idx = blockIdx.x * 256 + threadIdx.x;   // 4096*256 = 4194304/4 exact
    floatx4 t = v4[idx];
    out4[idx] = t;
    half4_t h;
    h[0] = (_Float16)t[0]; h[1] = (_Float16)t[1];
    h[2] = (_Float16)t[2]; h[3] = (_Float16)t[3];
    vf4[idx] = h;
}

// ---------------- kernel 2: Mt[j][i] = sum_o W2[o][j] * W1[o][i] ----------------
__global__ void mt_kernel(const float* __restrict__ W1,
                          const float* __restrict__ W2,
                          _Float16* __restrict__ Mt) {
    __shared__ float w2col[256];
    const int j = blockIdx.x;
    const int i = threadIdx.x;
    w2col[i] = W2[i * 256 + j];
    __syncthreads();
    float acc = 0.f;
    #pragma unroll 8
    for (int o = 0; o < 256; ++o)
        acc += w2col[o] * W1[o * 256 + i];
    Mt[j * 256 + i] = (_Float16)acc;
}

// ---------------- GEMM: C[m][n] = sum_k A[m,k]*Bm[n,k], K=256, tile 128x128 ----
// MFMA operand roles: A-op = n-frag, B-op = m-frag => D: n = quad*4+reg, m = l16.
// MODE 0: store half4 u-tile. MODE 1: p -> LDS, then coalesced streaming epilogue.
template<int MODE>
__global__ __launch_bounds__(256, 4)
void gemm_kernel(const _Float16* __restrict__ A, const _Float16* __restrict__ Bm,
                 size_t a_bstride, size_t b_bstride,
                 _Float16* __restrict__ Uout,
                 const float* __restrict__ adj, float* __restrict__ out) {
    __shared__ _Float16 smem[2 * 128 * LDSS];   // As | Bs ; reused as p-tile (128*PS)
    _Float16* As = smem;
    _Float16* Bs = smem + 128 * LDSS;

    const int tid  = threadIdx.x;
    const int lane = tid & 63;
    const int wid  = tid >> 6;
    const int wm   = wid >> 1;          // 2x2 wave grid, each wave 64(m)x64(n)
    const int wn   = wid & 1;
    const int quad = lane >> 4;
    const int l16  = lane & 15;

    const int m0 = blockIdx.x * 128;
    const int n0 = blockIdx.y * 128;
    const int batch = blockIdx.z;

    const _Float16* Ab = A  + (size_t)batch * a_bstride;
    const _Float16* Bb = Bm + (size_t)batch * b_bstride;

    floatx4 acc[4][4];   // acc[i][j]: i -> n-frag, j -> m-frag
    #pragma unroll
    for (int i = 0; i < 4; ++i)
        #pragma unroll
        for (int j = 0; j < 4; ++j)
            acc[i][j] = (floatx4){0.f, 0.f, 0.f, 0.f};

    const int rrow = tid >> 3;          // staging: 8 threads (8x16B) per 64-col row
    const int ch8  = (tid & 7) * 8;

    for (int kc = 0; kc < 256; kc += 64) {
        __syncthreads();
        #pragma unroll
        for (int r = 0; r < 4; ++r) {
            int row = r * 32 + rrow;
            uint4 va = *(const uint4*)(Ab + (((size_t)(m0 + row)) << 8) + kc + ch8);
            uint4 vb = *(const uint4*)(Bb + (((size_t)(n0 + row)) << 8) + kc + ch8);
            *(uint4*)(&As[row * LDSS + ch8]) = va;
            *(uint4*)(&Bs[row * LDSS + ch8]) = vb;
        }
        __syncthreads();
        #pragma unroll
        for (int ks = 0; ks < 2; ++ks) {
            const int kof = ks * 32 + quad * 8;   // operand layout: [row=lane&15][k=quad*8+j]
            half8_t mf[4], nf[4];
            #pragma unroll
            for (int t = 0; t < 4; ++t) {
                mf[t] = *(const half8_t*)(&As[(wm * 64 + t * 16 + l16) * LDSS + kof]);
                nf[t] = *(const half8_t*)(&Bs[(wn * 64 + t * 16 + l16) * LDSS + kof]);
            }
            #pragma unroll
            for (int i = 0; i < 4; ++i)
                #pragma unroll
                for (int j = 0; j < 4; ++j)
                    acc[i][j] = __builtin_amdgcn_mfma_f32_16x16x32_f16(
                        nf[i], mf[j], acc[i][j], 0, 0, 0);   // A-op = n, B-op = m
        }
    }

    if (MODE == 0) {
        // D layout: n = quad*4 + reg, m = l16
        #pragma unroll
        for (int j = 0; j < 4; ++j) {
            int m = m0 + wm * 64 + j * 16 + l16;        // u row
            #pragma unroll
            for (int i = 0; i < 4; ++i) {
                int n = wn * 64 + i * 16 + quad * 4;    // u col (grid.y covers n0)
                half4_t h;
                #pragma unroll
                for (int r = 0; r < 4; ++r) h[r] = (_Float16)acc[i][j][r];
                *(half4_t*)(Uout + (size_t)m * 256 + n0 + n) = h;
            }
        }
    } else {
        // Phase 1: p = 100*sigmoid(s) + 1e-5 -> f16 LDS tile (layout transform)
        __syncthreads();                      // all waves done reading As/Bs
        _Float16* Ps = smem;                  // 128 * PS * 2 = 33792 B <= 36864 B
        #pragma unroll
        for (int j = 0; j < 4; ++j) {
            int ml = wm * 64 + j * 16 + l16;
            #pragma unroll
            for (int i = 0; i < 4; ++i) {
                int nl = wn * 64 + i * 16 + quad * 4;
                half4_t h;
                #pragma unroll
                for (int r = 0; r < 4; ++r) {
                    float s = acc[i][j][r];
                    float p = 100.0f / (1.0f + __expf(-s)) + 1e-5f;
                    h[r] = (_Float16)p;
                }
                *(half4_t*)(&Ps[ml * PS + nl]) = h;
            }
        }
        __syncthreads();

        // Phase 2: fully-coalesced streaming epilogue.
        // 16 passes x 1024 elems: thread t -> row = pass*8 + t/32, col = (t%32)*4
        const int srow = tid >> 5;            // 0..7
        const int scol = (tid & 31) * 4;
        const size_t gbase = (size_t)batch * 2048 * 2048
                           + (size_t)m0 * 2048 + n0 + scol;
        #pragma unroll 4
        for (int pass = 0; pass < 16; ++pass) {
            int r = pass * 8 + srow;
            size_t g = gbase + (size_t)r * 2048;
            floatx4 a = *(const floatx4*)(adj + g);
            half4_t ph = *(const half4_t*)(&Ps[r * PS + scol]);
            floatx4 o;
            #pragma unroll
            for (int e = 0; e < 4; ++e) {
                float ip = __builtin_amdgcn_rcpf((float)ph[e]);
                float q = a[e] * ip;
                o[e] = __expf(-0.5f * q * q);
            }
            __builtin_nontemporal_store(o, (floatx4*)(out + g));
        }
    }
}

extern "C" void kernel_launch(void* const* d_in, const int* in_sizes, int n_in,
                              void* d_out, int out_size, void* d_ws, size_t ws_size,
                              hipStream_t stream) {
    const float* v   = (const float*)d_in[0];   // [8,2048,256]
    const float* adj = (const float*)d_in[1];   // [8,2048,2048]
    const float* W1  = (const float*)d_in[2];   // [256,256]
    const float* W2  = (const float*)d_in[3];   // [256,256]

    float* out_v   = (float*)d_out;                              // output 0: v copy
    float* out_adj = (float*)d_out + (size_t)8 * 2048 * 256;     // output 1

    char* ws = (char*)d_ws;
    _Float16* vf = (_Float16*)ws;                          // 8 MiB  [8*2048,256] f16
    _Float16* uf = (_Float16*)(ws + ((size_t)8 << 20));    // 8 MiB  [8*2048,256] f16
    _Float16* Mt = (_Float16*)(ws + ((size_t)16 << 20));   // 128 KiB [256,256] f16 (M^T)

    prep_kernel<<<4096, 256, 0, stream>>>((const floatx4*)v, (floatx4*)out_v, (half4_t*)vf);
    mt_kernel<<<256, 256, 0, stream>>>(W1, W2, Mt);
    // u = v * M : A rows = 16384 (all batches flat), Bm = Mt (256 rows)
    gemm_kernel<0><<<dim3(128, 2, 1), 256, 0, stream>>>(
        vf, Mt, 0, 0, uf, nullptr, nullptr);
    // s = u * v^T per batch + fused epilogue
    gemm_kernel<1><<<dim3(16, 16, 8), 256, 0, stream>>>(
        uf, vf, (size_t)2048 * 256, (size_t)2048 * 256, nullptr, adj, out_adj);
}